// Round 2
// baseline (702.573 us; speedup 1.0000x reference)
//
#include <hip/hip_runtime.h>

#define N_NODES 500000
#define N_EDGES 5000000
#define D 16

// ---------------------------------------------------------------------------
// Scatter-add: agg[dst[e]][d] += feat[src[e]][d]
// One thread per (edge, d): tid = e*16 + d. A 64-lane wave covers 4 edges,
// each edge's 16 lanes do one coalesced 64B read of feat[src] and one
// coalesced 64B atomic-add region on agg[dst].
// ---------------------------------------------------------------------------
__global__ __launch_bounds__(256) void scatter_add_kernel(
    const float* __restrict__ feat,
    const int* __restrict__ edge_index,   // [2, E]: src row then dst row
    float* __restrict__ agg) {
    long tid = (long)blockIdx.x * blockDim.x + threadIdx.x;
    long total = (long)N_EDGES * D;
    if (tid >= total) return;
    int e = (int)(tid >> 4);
    int d = (int)(tid & 15);
    int s = edge_index[e];
    int t = edge_index[N_EDGES + e];
    float v = feat[(long)s * D + d];
    atomicAdd(&agg[(long)t * D + d], v);
}

// ---------------------------------------------------------------------------
// Node kernel, layer 1: h[i] = relu(agg[i] @ Wrel^T + b + x[i] @ Wroot^T)
// ---------------------------------------------------------------------------
__global__ __launch_bounds__(256) void node1_kernel(
    const float* __restrict__ x,
    const float* __restrict__ agg,
    const float* __restrict__ w_rel,   // [D][D], out[d] uses row d
    const float* __restrict__ b_rel,   // [D]
    const float* __restrict__ w_root,  // [D][D]
    float* __restrict__ h) {
    __shared__ float sWrel[D * D];
    __shared__ float sWroot[D * D];
    __shared__ float sB[D];
    for (int i = threadIdx.x; i < D * D; i += blockDim.x) {
        sWrel[i] = w_rel[i];
        sWroot[i] = w_root[i];
    }
    if (threadIdx.x < D) sB[threadIdx.x] = b_rel[threadIdx.x];
    __syncthreads();

    int i = blockIdx.x * blockDim.x + threadIdx.x;
    if (i >= N_NODES) return;

    float a[D], xi[D];
    {
        const float4* ap = (const float4*)(agg + (long)i * D);
        const float4* xp = (const float4*)(x + (long)i * D);
        #pragma unroll
        for (int q = 0; q < 4; ++q) {
            float4 av = ap[q];
            float4 xv = xp[q];
            a[q * 4 + 0] = av.x; a[q * 4 + 1] = av.y; a[q * 4 + 2] = av.z; a[q * 4 + 3] = av.w;
            xi[q * 4 + 0] = xv.x; xi[q * 4 + 1] = xv.y; xi[q * 4 + 2] = xv.z; xi[q * 4 + 3] = xv.w;
        }
    }

    float4* hp = (float4*)(h + (long)i * D);
    #pragma unroll
    for (int q = 0; q < 4; ++q) {
        float4 o;
        float* op = &o.x;
        #pragma unroll
        for (int r = 0; r < 4; ++r) {
            int dd = q * 4 + r;
            float acc = sB[dd];
            #pragma unroll
            for (int k = 0; k < D; ++k)
                acc += a[k] * sWrel[dd * D + k] + xi[k] * sWroot[dd * D + k];
            op[r] = acc > 0.f ? acc : 0.f;
        }
        hp[q] = o;
    }
}

// ---------------------------------------------------------------------------
// Node kernel, layer 2 + MLP head:
// h2 = relu(agg @ W2rel^T + b2 + h1 @ W2root^T)
// h3 = relu(h2 @ fc1^T + b); out = h3 @ fc2^T + b
// ---------------------------------------------------------------------------
__global__ __launch_bounds__(256) void node2_kernel(
    const float* __restrict__ h1,
    const float* __restrict__ agg,
    const float* __restrict__ w_rel,
    const float* __restrict__ b_rel,
    const float* __restrict__ w_root,
    const float* __restrict__ fc1_w,  // [8][16]
    const float* __restrict__ fc1_b,  // [8]
    const float* __restrict__ fc2_w,  // [2][8]
    const float* __restrict__ fc2_b,  // [2]
    float* __restrict__ out) {
    __shared__ float sWrel[D * D];
    __shared__ float sWroot[D * D];
    __shared__ float sB[D];
    __shared__ float sF1w[8 * D];
    __shared__ float sF1b[8];
    __shared__ float sF2w[2 * 8];
    __shared__ float sF2b[2];
    for (int i = threadIdx.x; i < D * D; i += blockDim.x) {
        sWrel[i] = w_rel[i];
        sWroot[i] = w_root[i];
    }
    if (threadIdx.x < D) sB[threadIdx.x] = b_rel[threadIdx.x];
    if (threadIdx.x < 8 * D) sF1w[threadIdx.x] = fc1_w[threadIdx.x];
    if (threadIdx.x < 8) sF1b[threadIdx.x] = fc1_b[threadIdx.x];
    if (threadIdx.x < 16) sF2w[threadIdx.x] = fc2_w[threadIdx.x];
    if (threadIdx.x < 2) sF2b[threadIdx.x] = fc2_b[threadIdx.x];
    __syncthreads();

    int i = blockIdx.x * blockDim.x + threadIdx.x;
    if (i >= N_NODES) return;

    float a[D], xi[D];
    {
        const float4* ap = (const float4*)(agg + (long)i * D);
        const float4* xp = (const float4*)(h1 + (long)i * D);
        #pragma unroll
        for (int q = 0; q < 4; ++q) {
            float4 av = ap[q];
            float4 xv = xp[q];
            a[q * 4 + 0] = av.x; a[q * 4 + 1] = av.y; a[q * 4 + 2] = av.z; a[q * 4 + 3] = av.w;
            xi[q * 4 + 0] = xv.x; xi[q * 4 + 1] = xv.y; xi[q * 4 + 2] = xv.z; xi[q * 4 + 3] = xv.w;
        }
    }

    float h2[D];
    #pragma unroll
    for (int dd = 0; dd < D; ++dd) {
        float acc = sB[dd];
        #pragma unroll
        for (int k = 0; k < D; ++k)
            acc += a[k] * sWrel[dd * D + k] + xi[k] * sWroot[dd * D + k];
        h2[dd] = acc > 0.f ? acc : 0.f;
    }

    float h3[8];
    #pragma unroll
    for (int j = 0; j < 8; ++j) {
        float acc = sF1b[j];
        #pragma unroll
        for (int k = 0; k < D; ++k) acc += h2[k] * sF1w[j * D + k];
        h3[j] = acc > 0.f ? acc : 0.f;
    }

    float2 o;
    {
        float acc0 = sF2b[0], acc1 = sF2b[1];
        #pragma unroll
        for (int j = 0; j < 8; ++j) {
            acc0 += h3[j] * sF2w[0 * 8 + j];
            acc1 += h3[j] * sF2w[1 * 8 + j];
        }
        o.x = acc0;
        o.y = acc1;
    }
    ((float2*)out)[i] = o;
}

extern "C" void kernel_launch(void* const* d_in, const int* in_sizes, int n_in,
                              void* d_out, int out_size, void* d_ws, size_t ws_size,
                              hipStream_t stream) {
    const float* x          = (const float*)d_in[0];
    const int*   edge_index = (const int*)d_in[1];
    const float* c1_wrel    = (const float*)d_in[2];
    const float* c1_brel    = (const float*)d_in[3];
    const float* c1_wroot   = (const float*)d_in[4];
    const float* c2_wrel    = (const float*)d_in[5];
    const float* c2_brel    = (const float*)d_in[6];
    const float* c2_wroot   = (const float*)d_in[7];
    const float* fc1_w      = (const float*)d_in[8];
    const float* fc1_b      = (const float*)d_in[9];
    const float* fc2_w      = (const float*)d_in[10];
    const float* fc2_b      = (const float*)d_in[11];
    float* out = (float*)d_out;

    // Workspace layout: agg [N*D] floats, h1 [N*D] floats
    float* agg = (float*)d_ws;
    float* h1  = agg + (long)N_NODES * D;
    size_t feat_bytes = (size_t)N_NODES * D * sizeof(float);

    const int BLK = 256;
    long scatter_total = (long)N_EDGES * D;
    int scatter_blocks = (int)((scatter_total + BLK - 1) / BLK);
    int node_blocks = (N_NODES + BLK - 1) / BLK;

    // Layer 1
    hipMemsetAsync(agg, 0, feat_bytes, stream);
    scatter_add_kernel<<<scatter_blocks, BLK, 0, stream>>>(x, edge_index, agg);
    node1_kernel<<<node_blocks, BLK, 0, stream>>>(x, agg, c1_wrel, c1_brel, c1_wroot, h1);

    // Layer 2 + head
    hipMemsetAsync(agg, 0, feat_bytes, stream);
    scatter_add_kernel<<<scatter_blocks, BLK, 0, stream>>>(h1, edge_index, agg);
    node2_kernel<<<node_blocks, BLK, 0, stream>>>(h1, agg, c2_wrel, c2_brel, c2_wroot,
                                                  fc1_w, fc1_b, fc2_w, fc2_b, out);
}